// Round 10
// baseline (411.422 us; speedup 1.0000x reference)
//
#include <hip/hip_runtime.h>
#include <hip/hip_bf16.h>

#define SDIM 128
#define NCOL 16384          // SDIM*SDIM
#define ROWS_TOTAL 4096     // 4*1024

using bf16x8 = __attribute__((ext_vector_type(8))) __bf16;
using su8    = __attribute__((ext_vector_type(8))) ushort;
using f32x4  = __attribute__((ext_vector_type(4))) float;

// f32 -> bf16 (RNE) via the HW cast — compiler pairs these into v_cvt_pk_bf16_f32
__device__ __forceinline__ ushort f2bf(float f) {
  __hip_bfloat16 h = __float2bfloat16(f);
  union { __hip_bfloat16 h; ushort u; } c; c.h = h;
  return c.u;
}

// ---- prep: L,R f32 -> bf16 in fragment-major layout ----
// out[(((t1*4+ks)*8+tb)*4+g)*16+tl][8] = in[t1][tb*16+tl][ks*32+g*8 + 0..8)
__global__ __launch_bounds__(256) void k_prep(const float* __restrict__ L,
                                              const float* __restrict__ R,
                                              ushort* __restrict__ Lt,
                                              ushort* __restrict__ Rt) {
  int id = blockIdx.x * 256 + threadIdx.x;    // 0 .. 524287
  const float* in = (id < 262144) ? L : R;
  ushort* outp    = (id < 262144) ? Lt : Rt;
  int t  = id & 262143;
  int t1 = t >> 11;
  int ks = (t >> 9) & 3;
  int tb = (t >> 6) & 7;
  int g  = (t >> 4) & 3;
  int tl = t & 15;
  const float* src = in + (size_t)(t1 * 128 + tb * 16 + tl) * 128 + ks * 32 + g * 8;
  float4 a = *reinterpret_cast<const float4*>(src);
  float4 b = *reinterpret_cast<const float4*>(src + 4);
  su8 o;
  o[0] = f2bf(a.x); o[1] = f2bf(a.y); o[2] = f2bf(a.z); o[3] = f2bf(a.w);
  o[4] = f2bf(b.x); o[5] = f2bf(b.y); o[6] = f2bf(b.z); o[7] = f2bf(b.w);
  *reinterpret_cast<su8*>(outp + (size_t)t * 8) = o;
}

// ---- stage 1: T3 = sum_k L[m][j][k] * x[r][k*128+m], fragment-major output ----
// grid = rowtiles*16, 256 thr. block: 16 rows x 8 m's (mg). LDS 32 KB, one barrier.
// IDENTITY block mapping: xcd = bid%8 = mg&7, so each XCD touches only 2 of 16
// m-slices of Lt (512 KB -> L2-resident); x slabs served rt-concurrently from L3.
__global__ __launch_bounds__(256, 2) void k_stage1(const float* __restrict__ x,
                                                   const ushort* __restrict__ Lt,
                                                   ushort* __restrict__ T3,
                                                   int rowtiles) {
  unsigned bid = blockIdx.x;
  int rt = bid >> 4;
  int mg = bid & 15;
  int row0 = rt * 16;
  int m0 = mg * 8;

  __shared__ __align__(16) ushort xs[16384];  // [m 8][r 16][k 128], XOR-swizzled on r

  int tid = threadIdx.x;
  // ---- stage x slice into LDS (transpose m<->(r,k), f32->bf16) ----
  for (int t2 = 0; t2 < 2; ++t2) {
    int task = t2 * 256 + tid;                // 512 tasks
    int r = task >> 5, kq = task & 31;
    int k = kq << 2;
    const float4* p4 = reinterpret_cast<const float4*>(
        x + (size_t)(row0 + r) * NCOL + (size_t)k * SDIM + m0);
    ushort vv[4][8];
#pragma unroll
    for (int kk = 0; kk < 4; ++kk) {
      float4 a0 = p4[kk * 32 + 0];
      float4 a1 = p4[kk * 32 + 1];
      vv[kk][0] = f2bf(a0.x); vv[kk][1] = f2bf(a0.y);
      vv[kk][2] = f2bf(a0.z); vv[kk][3] = f2bf(a0.w);
      vv[kk][4] = f2bf(a1.x); vv[kk][5] = f2bf(a1.y);
      vv[kk][6] = f2bf(a1.z); vv[kk][7] = f2bf(a1.w);
    }
#pragma unroll
    for (int mm = 0; mm < 8; ++mm) {
      int e = ((mm * 16 + r) << 7) + k;
      int idx = e ^ ((r & 7) << 3);
      ushort4 w; w.x = vv[0][mm]; w.y = vv[1][mm]; w.z = vv[2][mm]; w.w = vv[3][mm];
      *reinterpret_cast<ushort4*>(&xs[idx]) = w;
    }
  }
  __syncthreads();

  int wave = tid >> 6, lane = tid & 63;
  int l15 = lane & 15, g = lane >> 4;
  int swz = (l15 & 7) << 3;

  const ushort* Lp = Lt + ((size_t)m0 * 32 + (size_t)wave * 2) * 512 + (size_t)lane * 8;

  f32x4 st[2][8];   // [jt][m], static indices via full unroll
  bf16x8 lf0[8], lf1[8];

  // preload m=0 L-frags
#pragma unroll
  for (int ks = 0; ks < 4; ++ks) {
    lf0[ks * 2 + 0] = *reinterpret_cast<const bf16x8*>(Lp + (size_t)(ks * 8 + 0) * 512);
    lf0[ks * 2 + 1] = *reinterpret_cast<const bf16x8*>(Lp + (size_t)(ks * 8 + 1) * 512);
  }

#pragma unroll
  for (int m = 0; m < 8; ++m) {
    // ---- issue next m's L-frags into the other buffer ----
    if (m < 7) {
      if ((m & 1) == 0) {
#pragma unroll
        for (int ks = 0; ks < 4; ++ks) {
          lf1[ks * 2 + 0] = *reinterpret_cast<const bf16x8*>(Lp + (size_t)(((m + 1) * 4 + ks) * 8 + 0) * 512);
          lf1[ks * 2 + 1] = *reinterpret_cast<const bf16x8*>(Lp + (size_t)(((m + 1) * 4 + ks) * 8 + 1) * 512);
        }
      } else {
#pragma unroll
        for (int ks = 0; ks < 4; ++ks) {
          lf0[ks * 2 + 0] = *reinterpret_cast<const bf16x8*>(Lp + (size_t)(((m + 1) * 4 + ks) * 8 + 0) * 512);
          lf0[ks * 2 + 1] = *reinterpret_cast<const bf16x8*>(Lp + (size_t)(((m + 1) * 4 + ks) * 8 + 1) * 512);
        }
      }
    }
    __builtin_amdgcn_sched_barrier(0);
    // ---- A-operand: X^T fragments from LDS ----
    bf16x8 xf[4];
#pragma unroll
    for (int ks = 0; ks < 4; ++ks) {
      int e = ((m * 16 + l15) << 7) + ks * 32 + g * 8;
      xf[ks] = *reinterpret_cast<const bf16x8*>(&xs[e ^ swz]);
    }
    f32x4 a0 = {0.f, 0.f, 0.f, 0.f};
    f32x4 a1 = {0.f, 0.f, 0.f, 0.f};
    if ((m & 1) == 0) {
#pragma unroll
      for (int ks = 0; ks < 4; ++ks) {
        a0 = __builtin_amdgcn_mfma_f32_16x16x32_bf16(xf[ks], lf0[ks * 2 + 0], a0, 0, 0, 0);
        a1 = __builtin_amdgcn_mfma_f32_16x16x32_bf16(xf[ks], lf0[ks * 2 + 1], a1, 0, 0, 0);
      }
    } else {
#pragma unroll
      for (int ks = 0; ks < 4; ++ks) {
        a0 = __builtin_amdgcn_mfma_f32_16x16x32_bf16(xf[ks], lf1[ks * 2 + 0], a0, 0, 0, 0);
        a1 = __builtin_amdgcn_mfma_f32_16x16x32_bf16(xf[ks], lf1[ks * 2 + 1], a1, 0, 0, 0);
      }
    }
    st[0][m] = a0;
    st[1][m] = a1;
  }

  // ---- epilogue: D[row=rr=g*4+v][col=j]; write fragment-major T3 runs ----
  int ks1 = mg >> 2, g2 = mg & 3;
#pragma unroll
  for (int jt = 0; jt < 2; ++jt) {
    int j = wave * 32 + jt * 16 + l15;
#pragma unroll
    for (int v = 0; v < 4; ++v) {
      int rr = g * 4 + v;
      su8 o;
      o[0] = f2bf(st[jt][0][v]); o[1] = f2bf(st[jt][1][v]);
      o[2] = f2bf(st[jt][2][v]); o[3] = f2bf(st[jt][3][v]);
      o[4] = f2bf(st[jt][4][v]); o[5] = f2bf(st[jt][5][v]);
      o[6] = f2bf(st[jt][6][v]); o[7] = f2bf(st[jt][7][v]);
      size_t a = (((size_t)(rt * 128 + j) * 4 + ks1) * 64 + g2 * 16 + rr) * 8;
      *reinterpret_cast<su8*>(T3 + a) = o;
    }
  }
}

// ---- stage 2: out[r][i*128+j] = sum_m R[j][i][m] * T[r][m][j] ----
// grid = rowtiles*16, 256 thr (4 waves x 16 i). jg PINNED TO XCD: each XCD's R
// slice = 512 KB -> L2-resident; ih partners adjacent -> T3 shared via L2.
// No LDS/barriers; 2-batch ping-pong keeps 16 x 1KB loads in flight.
__global__ __launch_bounds__(256, 2) void k_stage2(const ushort* __restrict__ T3,
                                                   const ushort* __restrict__ Rt,
                                                   float* __restrict__ out,
                                                   int rowtiles) {
  unsigned bid = blockIdx.x;              // grid = rowtiles*16, %8 == 0
  int jg = bid & 7;                       // pinned: one j-group per XCD
  int pos = bid >> 3;                     // 0 .. 2*rowtiles-1
  int ih = pos & 1;
  int rt = pos >> 1;
  int row0 = rt * 16;
  int j0 = jg * 16;

  int tid = threadIdx.x;
  int wave = tid >> 6, lane = tid & 63;
  int l15 = lane & 15, g = lane >> 4;
  int ib = ih * 4 + wave;          // i-block 0..7
  int ibase = ib * 16;

  f32x4 acc[16];
#pragma unroll
  for (int jj = 0; jj < 16; ++jj) acc[jj] = {0.f, 0.f, 0.f, 0.f};

  const ushort* Tp = T3 + (size_t)(rt * 128 + j0) * 4 * 512 + (size_t)lane * 8;
  const ushort* Rp = Rt + ((size_t)j0 * 32 + ib) * 512 + (size_t)lane * 8;

  bf16x8 a0[8], b0[8], a1[8], b1[8];
  // preload batch 0 (jj = 0,1)
#pragma unroll
  for (int u = 0; u < 2; ++u)
#pragma unroll
    for (int ks = 0; ks < 4; ++ks) {
      a0[u * 4 + ks] = *reinterpret_cast<const bf16x8*>(Tp + (size_t)(u * 4 + ks) * 512);
      b0[u * 4 + ks] = *reinterpret_cast<const bf16x8*>(Rp + (size_t)(u * 32 + ks * 8) * 512);
    }

#pragma unroll
  for (int p = 0; p < 8; ++p) {
    // ---- issue next batch (jj = 2p+2, 2p+3) into the other buffers ----
    if (p < 7) {
      int jn = (p + 1) * 2;
      if ((p & 1) == 0) {
#pragma unroll
        for (int u = 0; u < 2; ++u)
#pragma unroll
          for (int ks = 0; ks < 4; ++ks) {
            a1[u * 4 + ks] = *reinterpret_cast<const bf16x8*>(Tp + (size_t)((jn + u) * 4 + ks) * 512);
            b1[u * 4 + ks] = *reinterpret_cast<const bf16x8*>(Rp + (size_t)((jn + u) * 32 + ks * 8) * 512);
          }
      } else {
#pragma unroll
        for (int u = 0; u < 2; ++u)
#pragma unroll
          for (int ks = 0; ks < 4; ++ks) {
            a0[u * 4 + ks] = *reinterpret_cast<const bf16x8*>(Tp + (size_t)((jn + u) * 4 + ks) * 512);
            b0[u * 4 + ks] = *reinterpret_cast<const bf16x8*>(Rp + (size_t)((jn + u) * 32 + ks * 8) * 512);
          }
      }
    }
    __builtin_amdgcn_sched_barrier(0);
    // ---- consume current batch ----
    if ((p & 1) == 0) {
#pragma unroll
      for (int u = 0; u < 2; ++u)
#pragma unroll
        for (int ks = 0; ks < 4; ++ks)
          acc[p * 2 + u] = __builtin_amdgcn_mfma_f32_16x16x32_bf16(a0[u * 4 + ks], b0[u * 4 + ks], acc[p * 2 + u], 0, 0, 0);
    } else {
#pragma unroll
      for (int u = 0; u < 2; ++u)
#pragma unroll
        for (int ks = 0; ks < 4; ++ks)
          acc[p * 2 + u] = __builtin_amdgcn_mfma_f32_16x16x32_bf16(a1[u * 4 + ks], b1[u * 4 + ks], acc[p * 2 + u], 0, 0, 0);
    }
  }

  // ---- epilogue: each lane owns full 64B out lines, written back-to-back ----
#pragma unroll
  for (int v = 0; v < 4; ++v) {
    float* dst = out + (size_t)(row0 + g * 4 + v) * NCOL + (size_t)(ibase + l15) * SDIM + j0;
#pragma unroll
    for (int q = 0; q < 4; ++q) {
      float4 o; o.x = acc[q * 4 + 0][v]; o.y = acc[q * 4 + 1][v];
                o.z = acc[q * 4 + 2][v]; o.w = acc[q * 4 + 3][v];
      *reinterpret_cast<float4*>(dst + q * 4) = o;
    }
  }
}

extern "C" void kernel_launch(void* const* d_in, const int* in_sizes, int n_in,
                              void* d_out, int out_size, void* d_ws, size_t ws_size,
                              hipStream_t stream) {
  const float* x = (const float*)d_in[0];
  const float* L = (const float*)d_in[1];
  const float* R = (const float*)d_in[2];
  float* out = (float*)d_out;

  ushort* Lt = (ushort*)d_ws;
  ushort* Rt = Lt + 2097152;
  ushort* T3 = Rt + 2097152;
  const size_t lr_bytes = (size_t)2 * 2097152 * 2;
  size_t avail = ws_size > lr_bytes ? ws_size - lr_bytes : 0;
  // Chunk rows so the T3 round-trip stays cache-resident (chunk working set:
  // x 32MB + T3 16MB + out 32MB + Lt/Rt 8MB = 88MB << 256MB Infinity Cache).
  long long rpc = 512;
  long long fit = (long long)(avail / ((size_t)NCOL * 2));
  if (rpc > fit) rpc = fit;
  if (rpc > ROWS_TOTAL) rpc = ROWS_TOTAL;
  rpc &= ~15LL;
  if (rpc < 16) rpc = 16;

  k_prep<<<2048, 256, 0, stream>>>(L, R, Lt, Rt);

  for (long long row0 = 0; row0 < ROWS_TOTAL; row0 += rpc) {
    long long rows = (ROWS_TOTAL - row0 < rpc) ? (ROWS_TOTAL - row0) : rpc;
    int rowtiles = (int)(rows / 16);
    k_stage1<<<dim3(rowtiles * 16), 256, 0, stream>>>(x + row0 * NCOL, Lt, T3, rowtiles);
    k_stage2<<<dim3(rowtiles * 16), 256, 0, stream>>>(T3, Rt, out + row0 * NCOL, rowtiles);
  }
}

// Round 11
// 363.332 us; speedup vs baseline: 1.1324x; 1.1324x over previous
//
#include <hip/hip_runtime.h>
#include <hip/hip_bf16.h>

#define SDIM 128
#define NCOL 16384          // SDIM*SDIM
#define ROWS_TOTAL 4096     // 4*1024

using bf16x8 = __attribute__((ext_vector_type(8))) __bf16;
using su8    = __attribute__((ext_vector_type(8))) ushort;
using f32x4  = __attribute__((ext_vector_type(4))) float;

// f32 -> bf16 (RNE) via the HW cast — compiler pairs these into v_cvt_pk_bf16_f32
__device__ __forceinline__ ushort f2bf(float f) {
  __hip_bfloat16 h = __float2bfloat16(f);
  union { __hip_bfloat16 h; ushort u; } c; c.h = h;
  return c.u;
}

// ---- prep: L,R f32 -> bf16 in fragment-major layout ----
// out[(((t1*4+ks)*8+tb)*4+g)*16+tl][8] = in[t1][tb*16+tl][ks*32+g*8 + 0..8)
__global__ __launch_bounds__(256) void k_prep(const float* __restrict__ L,
                                              const float* __restrict__ R,
                                              ushort* __restrict__ Lt,
                                              ushort* __restrict__ Rt) {
  int id = blockIdx.x * 256 + threadIdx.x;    // 0 .. 524287
  const float* in = (id < 262144) ? L : R;
  ushort* outp    = (id < 262144) ? Lt : Rt;
  int t  = id & 262143;
  int t1 = t >> 11;
  int ks = (t >> 9) & 3;
  int tb = (t >> 6) & 7;
  int g  = (t >> 4) & 3;
  int tl = t & 15;
  const float* src = in + (size_t)(t1 * 128 + tb * 16 + tl) * 128 + ks * 32 + g * 8;
  float4 a = *reinterpret_cast<const float4*>(src);
  float4 b = *reinterpret_cast<const float4*>(src + 4);
  su8 o;
  o[0] = f2bf(a.x); o[1] = f2bf(a.y); o[2] = f2bf(a.z); o[3] = f2bf(a.w);
  o[4] = f2bf(b.x); o[5] = f2bf(b.y); o[6] = f2bf(b.z); o[7] = f2bf(b.w);
  *reinterpret_cast<su8*>(outp + (size_t)t * 8) = o;
}

// ---- stage 1: T3 = sum_k L[m][j][k] * x[r][k*128+m], fragment-major output ----
// grid = rowtiles*16, 256 thr. block: 16 rows x 8 m's (mg). LDS 32 KB, one barrier.
__global__ __launch_bounds__(256, 2) void k_stage1(const float* __restrict__ x,
                                                   const ushort* __restrict__ Lt,
                                                   ushort* __restrict__ T3,
                                                   int rowtiles) {
  unsigned nwg = gridDim.x;
  unsigned wg  = (blockIdx.x & 7u) * (nwg >> 3) + (blockIdx.x >> 3);  // XCD-contiguous
  int rt = wg >> 4;
  int mg = wg & 15;
  int row0 = rt * 16;
  int m0 = mg * 8;

  __shared__ __align__(16) ushort xs[16384];  // [m 8][r 16][k 128], XOR-swizzled on r

  int tid = threadIdx.x;
  // ---- stage x slice into LDS (transpose m<->(r,k), f32->bf16) ----
  for (int t2 = 0; t2 < 2; ++t2) {
    int task = t2 * 256 + tid;                // 512 tasks
    int r = task >> 5, kq = task & 31;
    int k = kq << 2;
    const float4* p4 = reinterpret_cast<const float4*>(
        x + (size_t)(row0 + r) * NCOL + (size_t)k * SDIM + m0);
    ushort vv[4][8];
#pragma unroll
    for (int kk = 0; kk < 4; ++kk) {
      float4 a0 = p4[kk * 32 + 0];
      float4 a1 = p4[kk * 32 + 1];
      vv[kk][0] = f2bf(a0.x); vv[kk][1] = f2bf(a0.y);
      vv[kk][2] = f2bf(a0.z); vv[kk][3] = f2bf(a0.w);
      vv[kk][4] = f2bf(a1.x); vv[kk][5] = f2bf(a1.y);
      vv[kk][6] = f2bf(a1.z); vv[kk][7] = f2bf(a1.w);
    }
#pragma unroll
    for (int mm = 0; mm < 8; ++mm) {
      int e = ((mm * 16 + r) << 7) + k;
      int idx = e ^ ((r & 7) << 3);
      ushort4 w; w.x = vv[0][mm]; w.y = vv[1][mm]; w.z = vv[2][mm]; w.w = vv[3][mm];
      *reinterpret_cast<ushort4*>(&xs[idx]) = w;
    }
  }
  __syncthreads();

  int wave = tid >> 6, lane = tid & 63;
  int l15 = lane & 15, g = lane >> 4;
  int swz = (l15 & 7) << 3;

  const ushort* Lp = Lt + ((size_t)m0 * 32 + (size_t)wave * 2) * 512 + (size_t)lane * 8;

  f32x4 st[2][8];   // [jt][m], static indices via full unroll
  bf16x8 lf0[8], lf1[8];

  // preload m=0 L-frags
#pragma unroll
  for (int ks = 0; ks < 4; ++ks) {
    lf0[ks * 2 + 0] = *reinterpret_cast<const bf16x8*>(Lp + (size_t)(ks * 8 + 0) * 512);
    lf0[ks * 2 + 1] = *reinterpret_cast<const bf16x8*>(Lp + (size_t)(ks * 8 + 1) * 512);
  }

#pragma unroll
  for (int m = 0; m < 8; ++m) {
    // ---- issue next m's L-frags into the other buffer ----
    if (m < 7) {
      if ((m & 1) == 0) {
#pragma unroll
        for (int ks = 0; ks < 4; ++ks) {
          lf1[ks * 2 + 0] = *reinterpret_cast<const bf16x8*>(Lp + (size_t)(((m + 1) * 4 + ks) * 8 + 0) * 512);
          lf1[ks * 2 + 1] = *reinterpret_cast<const bf16x8*>(Lp + (size_t)(((m + 1) * 4 + ks) * 8 + 1) * 512);
        }
      } else {
#pragma unroll
        for (int ks = 0; ks < 4; ++ks) {
          lf0[ks * 2 + 0] = *reinterpret_cast<const bf16x8*>(Lp + (size_t)(((m + 1) * 4 + ks) * 8 + 0) * 512);
          lf0[ks * 2 + 1] = *reinterpret_cast<const bf16x8*>(Lp + (size_t)(((m + 1) * 4 + ks) * 8 + 1) * 512);
        }
      }
    }
    __builtin_amdgcn_sched_barrier(0);
    // ---- A-operand: X^T fragments from LDS ----
    bf16x8 xf[4];
#pragma unroll
    for (int ks = 0; ks < 4; ++ks) {
      int e = ((m * 16 + l15) << 7) + ks * 32 + g * 8;
      xf[ks] = *reinterpret_cast<const bf16x8*>(&xs[e ^ swz]);
    }
    f32x4 a0 = {0.f, 0.f, 0.f, 0.f};
    f32x4 a1 = {0.f, 0.f, 0.f, 0.f};
    if ((m & 1) == 0) {
#pragma unroll
      for (int ks = 0; ks < 4; ++ks) {
        a0 = __builtin_amdgcn_mfma_f32_16x16x32_bf16(xf[ks], lf0[ks * 2 + 0], a0, 0, 0, 0);
        a1 = __builtin_amdgcn_mfma_f32_16x16x32_bf16(xf[ks], lf0[ks * 2 + 1], a1, 0, 0, 0);
      }
    } else {
#pragma unroll
      for (int ks = 0; ks < 4; ++ks) {
        a0 = __builtin_amdgcn_mfma_f32_16x16x32_bf16(xf[ks], lf1[ks * 2 + 0], a0, 0, 0, 0);
        a1 = __builtin_amdgcn_mfma_f32_16x16x32_bf16(xf[ks], lf1[ks * 2 + 1], a1, 0, 0, 0);
      }
    }
    st[0][m] = a0;
    st[1][m] = a1;
  }

  // ---- epilogue: D[row=rr=g*4+v][col=j]; write fragment-major T3 runs ----
  int ks1 = mg >> 2, g2 = mg & 3;
#pragma unroll
  for (int jt = 0; jt < 2; ++jt) {
    int j = wave * 32 + jt * 16 + l15;
#pragma unroll
    for (int v = 0; v < 4; ++v) {
      int rr = g * 4 + v;
      su8 o;
      o[0] = f2bf(st[jt][0][v]); o[1] = f2bf(st[jt][1][v]);
      o[2] = f2bf(st[jt][2][v]); o[3] = f2bf(st[jt][3][v]);
      o[4] = f2bf(st[jt][4][v]); o[5] = f2bf(st[jt][5][v]);
      o[6] = f2bf(st[jt][6][v]); o[7] = f2bf(st[jt][7][v]);
      size_t a = (((size_t)(rt * 128 + j) * 4 + ks1) * 64 + g2 * 16 + rr) * 8;
      *reinterpret_cast<su8*>(T3 + a) = o;
    }
  }
}

// ---- stage 2: out[r][i*128+j] = sum_m R[j][i][m] * T[r][m][j] ----
// grid = rowtiles*16, 256 thr (4 waves x 16 i). jg PINNED TO XCD: each XCD's R
// slice = 512 KB -> L2-resident; ih partners adjacent -> T3 shared via L2.
// No LDS/barriers; 2-batch ping-pong keeps 16 x 1KB loads in flight.
// launch_bounds (256,3): fit 3 waves/SIMD (12/CU) -- the one change this round.
__global__ __launch_bounds__(256, 3) void k_stage2(const ushort* __restrict__ T3,
                                                   const ushort* __restrict__ Rt,
                                                   float* __restrict__ out,
                                                   int rowtiles) {
  unsigned bid = blockIdx.x;              // grid = rowtiles*16, %8 == 0
  int jg = bid & 7;                       // pinned: one j-group per XCD
  int pos = bid >> 3;                     // 0 .. 2*rowtiles-1
  int ih = pos & 1;
  int rt = pos >> 1;
  int row0 = rt * 16;
  int j0 = jg * 16;

  int tid = threadIdx.x;
  int wave = tid >> 6, lane = tid & 63;
  int l15 = lane & 15, g = lane >> 4;
  int ib = ih * 4 + wave;          // i-block 0..7
  int ibase = ib * 16;

  f32x4 acc[16];
#pragma unroll
  for (int jj = 0; jj < 16; ++jj) acc[jj] = {0.f, 0.f, 0.f, 0.f};

  const ushort* Tp = T3 + (size_t)(rt * 128 + j0) * 4 * 512 + (size_t)lane * 8;
  const ushort* Rp = Rt + ((size_t)j0 * 32 + ib) * 512 + (size_t)lane * 8;

  bf16x8 a0[8], b0[8], a1[8], b1[8];
  // preload batch 0 (jj = 0,1)
#pragma unroll
  for (int u = 0; u < 2; ++u)
#pragma unroll
    for (int ks = 0; ks < 4; ++ks) {
      a0[u * 4 + ks] = *reinterpret_cast<const bf16x8*>(Tp + (size_t)(u * 4 + ks) * 512);
      b0[u * 4 + ks] = *reinterpret_cast<const bf16x8*>(Rp + (size_t)(u * 32 + ks * 8) * 512);
    }

#pragma unroll
  for (int p = 0; p < 8; ++p) {
    // ---- issue next batch (jj = 2p+2, 2p+3) into the other buffers ----
    if (p < 7) {
      int jn = (p + 1) * 2;
      if ((p & 1) == 0) {
#pragma unroll
        for (int u = 0; u < 2; ++u)
#pragma unroll
          for (int ks = 0; ks < 4; ++ks) {
            a1[u * 4 + ks] = *reinterpret_cast<const bf16x8*>(Tp + (size_t)((jn + u) * 4 + ks) * 512);
            b1[u * 4 + ks] = *reinterpret_cast<const bf16x8*>(Rp + (size_t)((jn + u) * 32 + ks * 8) * 512);
          }
      } else {
#pragma unroll
        for (int u = 0; u < 2; ++u)
#pragma unroll
          for (int ks = 0; ks < 4; ++ks) {
            a0[u * 4 + ks] = *reinterpret_cast<const bf16x8*>(Tp + (size_t)((jn + u) * 4 + ks) * 512);
            b0[u * 4 + ks] = *reinterpret_cast<const bf16x8*>(Rp + (size_t)((jn + u) * 32 + ks * 8) * 512);
          }
      }
    }
    __builtin_amdgcn_sched_barrier(0);
    // ---- consume current batch ----
    if ((p & 1) == 0) {
#pragma unroll
      for (int u = 0; u < 2; ++u)
#pragma unroll
        for (int ks = 0; ks < 4; ++ks)
          acc[p * 2 + u] = __builtin_amdgcn_mfma_f32_16x16x32_bf16(a0[u * 4 + ks], b0[u * 4 + ks], acc[p * 2 + u], 0, 0, 0);
    } else {
#pragma unroll
      for (int u = 0; u < 2; ++u)
#pragma unroll
        for (int ks = 0; ks < 4; ++ks)
          acc[p * 2 + u] = __builtin_amdgcn_mfma_f32_16x16x32_bf16(a1[u * 4 + ks], b1[u * 4 + ks], acc[p * 2 + u], 0, 0, 0);
    }
  }

  // ---- epilogue: each lane owns full 64B out lines, written back-to-back ----
#pragma unroll
  for (int v = 0; v < 4; ++v) {
    float* dst = out + (size_t)(row0 + g * 4 + v) * NCOL + (size_t)(ibase + l15) * SDIM + j0;
#pragma unroll
    for (int q = 0; q < 4; ++q) {
      float4 o; o.x = acc[q * 4 + 0][v]; o.y = acc[q * 4 + 1][v];
                o.z = acc[q * 4 + 2][v]; o.w = acc[q * 4 + 3][v];
      *reinterpret_cast<float4*>(dst + q * 4) = o;
    }
  }
}

extern "C" void kernel_launch(void* const* d_in, const int* in_sizes, int n_in,
                              void* d_out, int out_size, void* d_ws, size_t ws_size,
                              hipStream_t stream) {
  const float* x = (const float*)d_in[0];
  const float* L = (const float*)d_in[1];
  const float* R = (const float*)d_in[2];
  float* out = (float*)d_out;

  ushort* Lt = (ushort*)d_ws;
  ushort* Rt = Lt + 2097152;
  ushort* T3 = Rt + 2097152;
  const size_t lr_bytes = (size_t)2 * 2097152 * 2;
  size_t avail = ws_size > lr_bytes ? ws_size - lr_bytes : 0;
  // Chunk rows so the T3 round-trip stays L3-resident (chunk working set:
  // x 64MB + T3 32MB + out 64MB = 160MB < 256MB Infinity Cache).
  long long rpc = 1024;
  long long fit = (long long)(avail / ((size_t)NCOL * 2));
  if (rpc > fit) rpc = fit;
  if (rpc > ROWS_TOTAL) rpc = ROWS_TOTAL;
  rpc &= ~15LL;
  if (rpc < 16) rpc = 16;

  k_prep<<<2048, 256, 0, stream>>>(L, R, Lt, Rt);

  for (long long row0 = 0; row0 < ROWS_TOTAL; row0 += rpc) {
    long long rows = (ROWS_TOTAL - row0 < rpc) ? (ROWS_TOTAL - row0) : rpc;
    int rowtiles = (int)(rows / 16);
    k_stage1<<<dim3(rowtiles * 16), 256, 0, stream>>>(x + row0 * NCOL, Lt, T3, rowtiles);
    k_stage2<<<dim3(rowtiles * 16), 256, 0, stream>>>(T3, Rt, out + row0 * NCOL, rowtiles);
  }
}

// Round 12
// 343.900 us; speedup vs baseline: 1.1963x; 1.0565x over previous
//
#include <hip/hip_runtime.h>
#include <hip/hip_bf16.h>

#define SDIM 128
#define NCOL 16384          // SDIM*SDIM
#define ROWS_TOTAL 4096     // 4*1024

using bf16x8 = __attribute__((ext_vector_type(8))) __bf16;
using su8    = __attribute__((ext_vector_type(8))) ushort;
using f32x4  = __attribute__((ext_vector_type(4))) float;

// f32 -> bf16 (RNE) via the HW cast
__device__ __forceinline__ ushort f2bf(float f) {
  __hip_bfloat16 h = __float2bfloat16(f);
  union { __hip_bfloat16 h; ushort u; } c; c.h = h;
  return c.u;
}

// ---- prep: L,R f32 -> bf16 in fragment-major layout ----
// out[(((t1*4+ks)*8+tb)*4+g)*16+tl][8] = in[t1][tb*16+tl][ks*32+g*8 + 0..8)
__global__ __launch_bounds__(256) void k_prep(const float* __restrict__ L,
                                              const float* __restrict__ R,
                                              ushort* __restrict__ Lt,
                                              ushort* __restrict__ Rt) {
  int id = blockIdx.x * 256 + threadIdx.x;    // 0 .. 524287
  const float* in = (id < 262144) ? L : R;
  ushort* outp    = (id < 262144) ? Lt : Rt;
  int t  = id & 262143;
  int t1 = t >> 11;
  int ks = (t >> 9) & 3;
  int tb = (t >> 6) & 7;
  int g  = (t >> 4) & 3;
  int tl = t & 15;
  const float* src = in + (size_t)(t1 * 128 + tb * 16 + tl) * 128 + ks * 32 + g * 8;
  float4 a = *reinterpret_cast<const float4*>(src);
  float4 b = *reinterpret_cast<const float4*>(src + 4);
  su8 o;
  o[0] = f2bf(a.x); o[1] = f2bf(a.y); o[2] = f2bf(a.z); o[3] = f2bf(a.w);
  o[4] = f2bf(b.x); o[5] = f2bf(b.y); o[6] = f2bf(b.z); o[7] = f2bf(b.w);
  *reinterpret_cast<su8*>(outp + (size_t)t * 8) = o;
}

// ---- stage 1: T3 = sum_k L[m][j][k] * x[r][k*128+m], fragment-major output ----
// grid = rowtiles*16, 256 thr. block: 16 rows x 8 m's (mg). LDS 32 KB, one barrier.
// SIMPLE loads (no ping-pong): registers spent on occupancy instead (4 blocks/CU).
__global__ __launch_bounds__(256, 4) void k_stage1(const float* __restrict__ x,
                                                   const ushort* __restrict__ Lt,
                                                   ushort* __restrict__ T3,
                                                   int rowtiles) {
  unsigned nwg = gridDim.x;
  unsigned wg  = (blockIdx.x & 7u) * (nwg >> 3) + (blockIdx.x >> 3);  // XCD-contiguous
  int rt = wg >> 4;
  int mg = wg & 15;
  int row0 = rt * 16;
  int m0 = mg * 8;

  __shared__ __align__(16) ushort xs[16384];  // [m 8][r 16][k 128], XOR-swizzled on r

  int tid = threadIdx.x;
  // ---- stage x slice into LDS (transpose m<->(r,k), f32->bf16) ----
  for (int t2 = 0; t2 < 2; ++t2) {
    int task = t2 * 256 + tid;                // 512 tasks
    int r = task >> 5, kq = task & 31;
    int k = kq << 2;
    const float4* p4 = reinterpret_cast<const float4*>(
        x + (size_t)(row0 + r) * NCOL + (size_t)k * SDIM + m0);
    ushort vv[4][8];
#pragma unroll
    for (int kk = 0; kk < 4; ++kk) {
      float4 a0 = p4[kk * 32 + 0];
      float4 a1 = p4[kk * 32 + 1];
      vv[kk][0] = f2bf(a0.x); vv[kk][1] = f2bf(a0.y);
      vv[kk][2] = f2bf(a0.z); vv[kk][3] = f2bf(a0.w);
      vv[kk][4] = f2bf(a1.x); vv[kk][5] = f2bf(a1.y);
      vv[kk][6] = f2bf(a1.z); vv[kk][7] = f2bf(a1.w);
    }
#pragma unroll
    for (int mm = 0; mm < 8; ++mm) {
      int e = ((mm * 16 + r) << 7) + k;
      int idx = e ^ ((r & 7) << 3);
      ushort4 w; w.x = vv[0][mm]; w.y = vv[1][mm]; w.z = vv[2][mm]; w.w = vv[3][mm];
      *reinterpret_cast<ushort4*>(&xs[idx]) = w;
    }
  }
  __syncthreads();

  int wave = tid >> 6, lane = tid & 63;
  int l15 = lane & 15, g = lane >> 4;
  int swz = (l15 & 7) << 3;

  const ushort* Lp = Lt + ((size_t)m0 * 32 + (size_t)wave * 2) * 512 + (size_t)lane * 8;

  f32x4 st[2][8];   // [jt][m], static indices via full unroll

#pragma unroll
  for (int m = 0; m < 8; ++m) {
    // ---- A-operand: X^T fragments from LDS ----
    bf16x8 xf[4];
#pragma unroll
    for (int ks = 0; ks < 4; ++ks) {
      int e = ((m * 16 + l15) << 7) + ks * 32 + g * 8;
      xf[ks] = *reinterpret_cast<const bf16x8*>(&xs[e ^ swz]);
    }
    f32x4 a0 = {0.f, 0.f, 0.f, 0.f};
    f32x4 a1 = {0.f, 0.f, 0.f, 0.f};
#pragma unroll
    for (int ks = 0; ks < 4; ++ks) {
      bf16x8 l0 = *reinterpret_cast<const bf16x8*>(Lp + (size_t)((m * 4 + ks) * 8 + 0) * 512);
      bf16x8 l1 = *reinterpret_cast<const bf16x8*>(Lp + (size_t)((m * 4 + ks) * 8 + 1) * 512);
      a0 = __builtin_amdgcn_mfma_f32_16x16x32_bf16(xf[ks], l0, a0, 0, 0, 0);
      a1 = __builtin_amdgcn_mfma_f32_16x16x32_bf16(xf[ks], l1, a1, 0, 0, 0);
    }
    st[0][m] = a0;
    st[1][m] = a1;
  }

  // ---- epilogue: D[row=rr=g*4+v][col=j]; write fragment-major T3 runs ----
  int ks1 = mg >> 2, g2 = mg & 3;
#pragma unroll
  for (int jt = 0; jt < 2; ++jt) {
    int j = wave * 32 + jt * 16 + l15;
#pragma unroll
    for (int v = 0; v < 4; ++v) {
      int rr = g * 4 + v;
      su8 o;
      o[0] = f2bf(st[jt][0][v]); o[1] = f2bf(st[jt][1][v]);
      o[2] = f2bf(st[jt][2][v]); o[3] = f2bf(st[jt][3][v]);
      o[4] = f2bf(st[jt][4][v]); o[5] = f2bf(st[jt][5][v]);
      o[6] = f2bf(st[jt][6][v]); o[7] = f2bf(st[jt][7][v]);
      size_t a = (((size_t)(rt * 128 + j) * 4 + ks1) * 64 + g2 * 16 + rr) * 8;
      *reinterpret_cast<su8*>(T3 + a) = o;
    }
  }
}

// ---- stage 2: out[r][i*128+j] = sum_m R[j][i][m] * T[r][m][j] ----
// grid = rowtiles*16, 256 thr (4 waves x 16 i). jg PINNED TO XCD (R slice 512 KB
// L2-resident); ih partners adjacent (T3 shared via L2). No LDS/barriers.
// SIMPLE per-jj loads; acc[16] only -> low VGPR -> 4 blocks/CU (16 waves).
__global__ __launch_bounds__(256, 4) void k_stage2(const ushort* __restrict__ T3,
                                                   const ushort* __restrict__ Rt,
                                                   float* __restrict__ out,
                                                   int rowtiles) {
  unsigned bid = blockIdx.x;              // grid = rowtiles*16, %8 == 0
  int jg = bid & 7;                       // pinned: one j-group per XCD
  int pos = bid >> 3;                     // 0 .. 2*rowtiles-1
  int ih = pos & 1;
  int rt = pos >> 1;
  int row0 = rt * 16;
  int j0 = jg * 16;

  int tid = threadIdx.x;
  int wave = tid >> 6, lane = tid & 63;
  int l15 = lane & 15, g = lane >> 4;
  int ib = ih * 4 + wave;          // i-block 0..7
  int ibase = ib * 16;

  f32x4 acc[16];
#pragma unroll
  for (int jj = 0; jj < 16; ++jj) acc[jj] = {0.f, 0.f, 0.f, 0.f};

  const ushort* Tp = T3 + (size_t)(rt * 128 + j0) * 4 * 512 + (size_t)lane * 8;
  const ushort* Rp = Rt + ((size_t)j0 * 32 + ib) * 512 + (size_t)lane * 8;

#pragma unroll
  for (int jj = 0; jj < 16; ++jj) {
#pragma unroll
    for (int ks = 0; ks < 4; ++ks) {
      bf16x8 af = *reinterpret_cast<const bf16x8*>(Tp + (size_t)(jj * 4 + ks) * 512);
      bf16x8 bf = *reinterpret_cast<const bf16x8*>(Rp + (size_t)(jj * 32 + ks * 8) * 512);
      acc[jj] = __builtin_amdgcn_mfma_f32_16x16x32_bf16(af, bf, acc[jj], 0, 0, 0);
    }
  }

  // ---- epilogue: each lane owns full 64B out lines, written back-to-back ----
#pragma unroll
  for (int v = 0; v < 4; ++v) {
    float* dst = out + (size_t)(row0 + g * 4 + v) * NCOL + (size_t)(ibase + l15) * SDIM + j0;
#pragma unroll
    for (int q = 0; q < 4; ++q) {
      float4 o; o.x = acc[q * 4 + 0][v]; o.y = acc[q * 4 + 1][v];
                o.z = acc[q * 4 + 2][v]; o.w = acc[q * 4 + 3][v];
      *reinterpret_cast<float4*>(dst + q * 4) = o;
    }
  }
}

extern "C" void kernel_launch(void* const* d_in, const int* in_sizes, int n_in,
                              void* d_out, int out_size, void* d_ws, size_t ws_size,
                              hipStream_t stream) {
  const float* x = (const float*)d_in[0];
  const float* L = (const float*)d_in[1];
  const float* R = (const float*)d_in[2];
  float* out = (float*)d_out;

  ushort* Lt = (ushort*)d_ws;
  ushort* Rt = Lt + 2097152;
  ushort* T3 = Rt + 2097152;
  const size_t lr_bytes = (size_t)2 * 2097152 * 2;
  size_t avail = ws_size > lr_bytes ? ws_size - lr_bytes : 0;
  // Chunk rows so the T3 round-trip stays L3-resident (chunk working set:
  // x 64MB + T3 32MB + out 64MB = 160MB < 256MB Infinity Cache).
  long long rpc = 1024;
  long long fit = (long long)(avail / ((size_t)NCOL * 2));
  if (rpc > fit) rpc = fit;
  if (rpc > ROWS_TOTAL) rpc = ROWS_TOTAL;
  rpc &= ~15LL;
  if (rpc < 16) rpc = 16;

  k_prep<<<2048, 256, 0, stream>>>(L, R, Lt, Rt);

  for (long long row0 = 0; row0 < ROWS_TOTAL; row0 += rpc) {
    long long rows = (ROWS_TOTAL - row0 < rpc) ? (ROWS_TOTAL - row0) : rpc;
    int rowtiles = (int)(rows / 16);
    k_stage1<<<dim3(rowtiles * 16), 256, 0, stream>>>(x + row0 * NCOL, Lt, T3, rowtiles);
    k_stage2<<<dim3(rowtiles * 16), 256, 0, stream>>>(T3, Rt, out + row0 * NCOL, rowtiles);
  }
}

// Round 13
// 329.732 us; speedup vs baseline: 1.2477x; 1.0430x over previous
//
#include <hip/hip_runtime.h>
#include <hip/hip_bf16.h>

#define SDIM 128
#define NCOL 16384          // SDIM*SDIM
#define ROWS_TOTAL 4096     // 4*1024

using bf16x8 = __attribute__((ext_vector_type(8))) __bf16;
using su8    = __attribute__((ext_vector_type(8))) ushort;
using f32x4  = __attribute__((ext_vector_type(4))) float;

// f32 -> bf16 (RNE) via the HW cast
__device__ __forceinline__ ushort f2bf(float f) {
  __hip_bfloat16 h = __float2bfloat16(f);
  union { __hip_bfloat16 h; ushort u; } c; c.h = h;
  return c.u;
}

// ---- prep: L,R f32 -> bf16 in fragment-major layout ----
// out[(((t1*4+ks)*8+tb)*4+g)*16+tl][8] = in[t1][tb*16+tl][ks*32+g*8 + 0..8)
__global__ __launch_bounds__(256) void k_prep(const float* __restrict__ L,
                                              const float* __restrict__ R,
                                              ushort* __restrict__ Lt,
                                              ushort* __restrict__ Rt) {
  int id = blockIdx.x * 256 + threadIdx.x;    // 0 .. 524287
  const float* in = (id < 262144) ? L : R;
  ushort* outp    = (id < 262144) ? Lt : Rt;
  int t  = id & 262143;
  int t1 = t >> 11;
  int ks = (t >> 9) & 3;
  int tb = (t >> 6) & 7;
  int g  = (t >> 4) & 3;
  int tl = t & 15;
  const float* src = in + (size_t)(t1 * 128 + tb * 16 + tl) * 128 + ks * 32 + g * 8;
  float4 a = *reinterpret_cast<const float4*>(src);
  float4 b = *reinterpret_cast<const float4*>(src + 4);
  su8 o;
  o[0] = f2bf(a.x); o[1] = f2bf(a.y); o[2] = f2bf(a.z); o[3] = f2bf(a.w);
  o[4] = f2bf(b.x); o[5] = f2bf(b.y); o[6] = f2bf(b.z); o[7] = f2bf(b.w);
  *reinterpret_cast<su8*>(outp + (size_t)t * 8) = o;
}

// ---- stage 1: T3 = sum_k L[m][j][k] * x[r][k*128+m], fragment-major output ----
// grid = rowtiles*16, 256 thr. block: 16 rows x 8 m's (mg). LDS 32 KB, one barrier.
__global__ __launch_bounds__(256, 4) void k_stage1(const float* __restrict__ x,
                                                   const ushort* __restrict__ Lt,
                                                   ushort* __restrict__ T3,
                                                   int rowtiles) {
  unsigned nwg = gridDim.x;
  unsigned wg  = (blockIdx.x & 7u) * (nwg >> 3) + (blockIdx.x >> 3);  // XCD-contiguous
  int rt = wg >> 4;
  int mg = wg & 15;
  int row0 = rt * 16;
  int m0 = mg * 8;

  __shared__ __align__(16) ushort xs[16384];  // [m 8][r 16][k 128], XOR-swizzled on r

  int tid = threadIdx.x;
  // ---- stage x slice into LDS (transpose m<->(r,k), f32->bf16) ----
  for (int t2 = 0; t2 < 2; ++t2) {
    int task = t2 * 256 + tid;                // 512 tasks
    int r = task >> 5, kq = task & 31;
    int k = kq << 2;
    const float4* p4 = reinterpret_cast<const float4*>(
        x + (size_t)(row0 + r) * NCOL + (size_t)k * SDIM + m0);
    ushort vv[4][8];
#pragma unroll
    for (int kk = 0; kk < 4; ++kk) {
      float4 a0 = p4[kk * 32 + 0];
      float4 a1 = p4[kk * 32 + 1];
      vv[kk][0] = f2bf(a0.x); vv[kk][1] = f2bf(a0.y);
      vv[kk][2] = f2bf(a0.z); vv[kk][3] = f2bf(a0.w);
      vv[kk][4] = f2bf(a1.x); vv[kk][5] = f2bf(a1.y);
      vv[kk][6] = f2bf(a1.z); vv[kk][7] = f2bf(a1.w);
    }
#pragma unroll
    for (int mm = 0; mm < 8; ++mm) {
      int e = ((mm * 16 + r) << 7) + k;
      int idx = e ^ ((r & 7) << 3);
      ushort4 w; w.x = vv[0][mm]; w.y = vv[1][mm]; w.z = vv[2][mm]; w.w = vv[3][mm];
      *reinterpret_cast<ushort4*>(&xs[idx]) = w;
    }
  }
  __syncthreads();

  int wave = tid >> 6, lane = tid & 63;
  int l15 = lane & 15, g = lane >> 4;
  int swz = (l15 & 7) << 3;

  const ushort* Lp = Lt + ((size_t)m0 * 32 + (size_t)wave * 2) * 512 + (size_t)lane * 8;

  f32x4 st[2][8];   // [jt][m], static indices via full unroll

#pragma unroll
  for (int m = 0; m < 8; ++m) {
    // ---- A-operand: X^T fragments from LDS ----
    bf16x8 xf[4];
#pragma unroll
    for (int ks = 0; ks < 4; ++ks) {
      int e = ((m * 16 + l15) << 7) + ks * 32 + g * 8;
      xf[ks] = *reinterpret_cast<const bf16x8*>(&xs[e ^ swz]);
    }
    f32x4 a0 = {0.f, 0.f, 0.f, 0.f};
    f32x4 a1 = {0.f, 0.f, 0.f, 0.f};
#pragma unroll
    for (int ks = 0; ks < 4; ++ks) {
      bf16x8 l0 = *reinterpret_cast<const bf16x8*>(Lp + (size_t)((m * 4 + ks) * 8 + 0) * 512);
      bf16x8 l1 = *reinterpret_cast<const bf16x8*>(Lp + (size_t)((m * 4 + ks) * 8 + 1) * 512);
      a0 = __builtin_amdgcn_mfma_f32_16x16x32_bf16(xf[ks], l0, a0, 0, 0, 0);
      a1 = __builtin_amdgcn_mfma_f32_16x16x32_bf16(xf[ks], l1, a1, 0, 0, 0);
    }
    st[0][m] = a0;
    st[1][m] = a1;
  }

  // ---- epilogue: D[row=rr=g*4+v][col=j]; write fragment-major T3 runs ----
  int ks1 = mg >> 2, g2 = mg & 3;
#pragma unroll
  for (int jt = 0; jt < 2; ++jt) {
    int j = wave * 32 + jt * 16 + l15;
#pragma unroll
    for (int v = 0; v < 4; ++v) {
      int rr = g * 4 + v;
      su8 o;
      o[0] = f2bf(st[jt][0][v]); o[1] = f2bf(st[jt][1][v]);
      o[2] = f2bf(st[jt][2][v]); o[3] = f2bf(st[jt][3][v]);
      o[4] = f2bf(st[jt][4][v]); o[5] = f2bf(st[jt][5][v]);
      o[6] = f2bf(st[jt][6][v]); o[7] = f2bf(st[jt][7][v]);
      size_t a = (((size_t)(rt * 128 + j) * 4 + ks1) * 64 + g2 * 16 + rr) * 8;
      *reinterpret_cast<su8*>(T3 + a) = o;
    }
  }
}

// ---- stage 2: out[r][i*128+j] = sum_m R[j][i][m] * T[r][m][j] ----
// grid = rowtiles*8, 512 thr = 8 waves = all 128 i (no duplication anywhere).
// The block's T3 slice (64 KB, CONTIGUOUS in fragment-major layout) is staged
// into LDS once and ds_read by all 8 waves: af L3 traffic cut 4-8x vs per-wave
// global loads. bf (R) streams from the jg-pinned XCD's L2 (512 KB slice).
__global__ __launch_bounds__(512, 4) void k_stage2(const ushort* __restrict__ T3,
                                                   const ushort* __restrict__ Rt,
                                                   float* __restrict__ out,
                                                   int rowtiles) {
  unsigned bid = blockIdx.x;              // grid = rowtiles*8
  int jg = bid & 7;                       // pinned: one j-group per XCD
  int rt = bid >> 3;
  int row0 = rt * 16;
  int j0 = jg * 16;

  __shared__ __align__(16) ushort ts[32768];   // 64 KB linear copy of T3 slice

  int tid = threadIdx.x;                  // 0..511
  int wave = tid >> 6, lane = tid & 63;
  int l15 = lane & 15, g = lane >> 4;
  int ibase = wave * 16;

  // ---- stage af slice into LDS: 64 KB contiguous, 512 thr x 8 x 16B ----
  {
    const su8* s8 = reinterpret_cast<const su8*>(T3 + (size_t)(rt * 128 + j0) * 4 * 512);
    su8* d8 = reinterpret_cast<su8*>(ts);
#pragma unroll
    for (int q = 0; q < 8; ++q)
      d8[q * 512 + tid] = s8[q * 512 + tid];
  }
  __syncthreads();

  f32x4 acc[16];
#pragma unroll
  for (int jj = 0; jj < 16; ++jj) acc[jj] = {0.f, 0.f, 0.f, 0.f};

  const ushort* Rp = Rt + ((size_t)j0 * 32 + wave) * 512 + (size_t)lane * 8;
  const ushort* tp = ts + (size_t)lane * 8;

#pragma unroll
  for (int jj = 0; jj < 16; ++jj) {
#pragma unroll
    for (int ks = 0; ks < 4; ++ks) {
      bf16x8 af = *reinterpret_cast<const bf16x8*>(tp + (size_t)(jj * 4 + ks) * 512);
      bf16x8 bf = *reinterpret_cast<const bf16x8*>(Rp + (size_t)(jj * 32 + ks * 8) * 512);
      acc[jj] = __builtin_amdgcn_mfma_f32_16x16x32_bf16(af, bf, acc[jj], 0, 0, 0);
    }
  }

  // ---- epilogue: each lane owns full 64B out lines, written back-to-back ----
#pragma unroll
  for (int v = 0; v < 4; ++v) {
    float* dst = out + (size_t)(row0 + g * 4 + v) * NCOL + (size_t)(ibase + l15) * SDIM + j0;
#pragma unroll
    for (int q = 0; q < 4; ++q) {
      float4 o; o.x = acc[q * 4 + 0][v]; o.y = acc[q * 4 + 1][v];
                o.z = acc[q * 4 + 2][v]; o.w = acc[q * 4 + 3][v];
      *reinterpret_cast<float4*>(dst + q * 4) = o;
    }
  }
}

extern "C" void kernel_launch(void* const* d_in, const int* in_sizes, int n_in,
                              void* d_out, int out_size, void* d_ws, size_t ws_size,
                              hipStream_t stream) {
  const float* x = (const float*)d_in[0];
  const float* L = (const float*)d_in[1];
  const float* R = (const float*)d_in[2];
  float* out = (float*)d_out;

  ushort* Lt = (ushort*)d_ws;
  ushort* Rt = Lt + 2097152;
  ushort* T3 = Rt + 2097152;
  const size_t lr_bytes = (size_t)2 * 2097152 * 2;
  size_t avail = ws_size > lr_bytes ? ws_size - lr_bytes : 0;
  // Chunk rows so the T3 round-trip stays L3-resident (chunk working set:
  // x 64MB + T3 32MB + out 64MB = 160MB < 256MB Infinity Cache).
  long long rpc = 1024;
  long long fit = (long long)(avail / ((size_t)NCOL * 2));
  if (rpc > fit) rpc = fit;
  if (rpc > ROWS_TOTAL) rpc = ROWS_TOTAL;
  rpc &= ~15LL;
  if (rpc < 16) rpc = 16;

  k_prep<<<2048, 256, 0, stream>>>(L, R, Lt, Rt);

  for (long long row0 = 0; row0 < ROWS_TOTAL; row0 += rpc) {
    long long rows = (ROWS_TOTAL - row0 < rpc) ? (ROWS_TOTAL - row0) : rpc;
    int rowtiles = (int)(rows / 16);
    k_stage1<<<dim3(rowtiles * 16), 256, 0, stream>>>(x + row0 * NCOL, Lt, T3, rowtiles);
    k_stage2<<<dim3(rowtiles * 8), 512, 0, stream>>>(T3, Rt, out + row0 * NCOL, rowtiles);
  }
}